// Round 3
// baseline (920.653 us; speedup 1.0000x reference)
//
#include <hip/hip_runtime.h>

typedef _Float16 half8 __attribute__((ext_vector_type(8)));
typedef float f32x4 __attribute__((ext_vector_type(4)));
typedef unsigned int u32x4 __attribute__((ext_vector_type(4)));

#define SC_AGENT __HIP_MEMORY_SCOPE_AGENT

// Problem: B=16, T=64, L=64, H=256. K=2H=512, N=4H=1024.
//
// Tag-in-word protocol: h published as 8B words [h0 f16 | h1 f16 | tag=t | 0]
// via agent-scope relaxed atomic store (write-through: home L2 + IC).
// Consumers poll their own words; tag match <=> payload valid (8B atomicity).
//
// Round-3 poll tiers:
//   tier-A (3 of 4 rounds): inline-asm global_load_dwordx4 ... sc0 -- bypasses
//     L1, served by the XCD-shared L2. With the XCD-affine remap (layers
//     8k..8k+7 share XCD k), producer write-through should land in the same
//     L2 -> ~100-200ns detection.
//   tier-B (every 4th round): agent-scope atomic loads (sc0 sc1 -> IC).
//     Guaranteed fresh regardless of actual WG->XCD placement; bounds
//     detection lag, prevents livelock on stale L2 lines. Correctness never
//     depends on the placement heuristic (G16).
//
// Publish: register lane-pair pack (shfl_xor) -> 4 agent stores from even
// lanes. No hLds, no pre-publish barrier.
//
// Backpressure: prog[wg] = latest staged t. Producer may overwrite slot t&1
// (holding t-2) once all 4 consumer WGs of layer l+1 have prog >= t-2.
//
// ws layout: prog[256] int at 0; Hw at 64KB: 2 slots * 64l * 16b * 128w * 8B = 2MB.
constexpr size_t OFF_PROG = 0;
constexpr size_t OFF_H    = 65536;
constexpr size_t SLOT_STRIDE = (size_t)64 * 16 * 128;  // words per slot

__device__ __forceinline__ size_t Widx(int l, int b, int wi) {
  return ((size_t)l * 16 + b) * 128 + wi;
}
__device__ __forceinline__ int wgid(int l, int r) {
  return (((l & 7) * 4 + r) << 3) | (l >> 3);  // inverse of the (l,r) remap
}
__device__ __forceinline__ float sigm(float v) { return 1.0f / (1.0f + __expf(-v)); }
__device__ __forceinline__ float tanh_(float v) { return 1.0f - 2.0f / (__expf(2.0f * v) + 1.0f); }

// ---------------- init: prog=-1, slot0 tags invalid, slot1 = h(l,-1) tag 0xFFFF ----
__global__ void init_ws(const float* __restrict__ init_state, char* ws) {
  int* prog = (int*)(ws + OFF_PROG);
  unsigned long long* Hw = (unsigned long long*)(ws + OFF_H);
  const int tid = blockIdx.x * 256 + threadIdx.x;  // 65536 threads
  if (tid < 256) prog[tid] = -1;
  for (int e = tid; e < 64 * 16 * 128; e += 65536) {
    const int wi = e & 127, b = (e >> 7) & 15, l = e >> 11;
    Hw[Widx(l, b, wi)] = 0xFFFE00000000ULL;  // slot0: tag 0xFFFE (never matches)
    union { _Float16 f; unsigned short s; } h0, h1;
    h0.f = (_Float16)init_state[((l * 2 + 1) * 16 + b) * 256 + 2 * wi];
    h1.f = (_Float16)init_state[((l * 2 + 1) * 16 + b) * 256 + 2 * wi + 1];
    Hw[SLOT_STRIDE + Widx(l, b, wi)] =
        (unsigned long long)h0.s | ((unsigned long long)h1.s << 16) | (0xFFFFULL << 32);
  }
}

// ---------------- main: 256 WGs; XCD-affine (l,r) from wg ----------------
__global__ __launch_bounds__(256, 1) void lstm_mfma(
    const float* __restrict__ x, const float* __restrict__ init_state,
    const float* __restrict__ W, const float* __restrict__ bias,
    float* __restrict__ out, char* ws) {
  int* prog = (int*)(ws + OFF_PROG);
  unsigned long long* Hw = (unsigned long long*)(ws + OFF_H);

  const int tid = threadIdx.x;
  const int wg = blockIdx.x;
  const int l = ((wg & 7) << 3) | (wg >> 5);  // layers 8k..8k+7 share XCD k
  const int r = (wg >> 3) & 3;
  const int wv = tid >> 6, lane = tid & 63;

  __shared__ alignas(16) _Float16 aLds[16 * 64 * 8];  // A-frags: [kb][lane][8], 16 KB
  __shared__ alignas(16) float zLds[16 * 260];        // z transpose, 16.6 KB

  // ---- W slice -> registers (unchanged) ----
  half8 wreg[64];
#pragma unroll
  for (int q = 0; q < 4; ++q) {
    const int nl = (wv * 4 + q) * 16 + (lane & 15);
    const int col = (nl & 3) * 256 + r * 64 + (nl >> 2);
#pragma unroll
    for (int kb = 0; kb < 16; ++kb) {
      const int k0 = kb * 32 + (lane >> 4) * 8;
      const float* src = W + (size_t)k0 * 1024 + col;
      half8 hv;
#pragma unroll
      for (int jj = 0; jj < 8; ++jj) hv[jj] = (_Float16)src[(size_t)jj * 1024];
      wreg[q * 16 + kb] = hv;
    }
  }

  // ---- per-thread epilogue identity ----
  const int hu = tid & 63, b4 = tid >> 6;
  const int gu = r * 64 + hu;
  float creg[4];
#pragma unroll
  for (int bb = 0; bb < 4; ++bb)
    creg[bb] = init_state[((l * 2 + 0) * 16 + (b4 * 4 + bb)) * 256 + gu];
  const float bi_ = bias[0 * 256 + gu], bj_ = bias[1 * 256 + gu];
  const float bf_ = bias[2 * 256 + gu], bo_ = bias[3 * 256 + gu];

  // ---- staging entry invariants ----
  int kbA[4], lnA[4];
  size_t wbase[4];
#pragma unroll
  for (int i = 0; i < 4; ++i) {
    const int e = i * 256 + tid, kb = e >> 6, ln = e & 63;
    const int m = ln & 15, k0 = kb * 32 + (ln >> 4) * 8;
    kbA[i] = kb; lnA[i] = ln;
    wbase[i] = (i < 2) ? (l > 0 ? Widx(l - 1, m, k0 >> 1) : 0)
                       : Widx(l, m, (k0 - 256) >> 1);
  }

  // ---- backpressure addresses (remapped wg indices) ----
  int* const bpp0 = &prog[wgid(l < 63 ? l + 1 : 63, 0)];
  int* const bpp1 = &prog[wgid(l < 63 ? l + 1 : 63, 1)];
  int* const bpp2 = &prog[wgid(l < 63 ? l + 1 : 63, 2)];
  int* const bpp3 = &prog[wgid(l < 63 ? l + 1 : 63, 3)];

  for (int t = 0; t < 64; ++t) {
    const int slotCur = t & 1, slotPrev = (t + 1) & 1;
    const unsigned expIn = (unsigned)(unsigned short)t;        // h(l-1,t)
    const unsigned expOwn = (unsigned)(unsigned short)(t - 1); // h(l,t-1); t=0 -> 0xFFFF

    if (l == 0) {
#pragma unroll
      for (int i = 0; i < 2; ++i) {
        const int kb = kbA[i], ln = lnA[i];
        const int m = ln & 15, k0 = kb * 32 + (ln >> 4) * 8;
        const float* xs = x + ((size_t)m * 64 + t) * 256 + k0;
        half8 hv;
#pragma unroll
        for (int jj = 0; jj < 8; ++jj) hv[jj] = (_Float16)xs[jj];
        *(half8*)&aLds[(size_t)(kb * 64 + ln) * 8] = hv;
      }
    }

    // ---- poll+stage ----
    unsigned pend = (l == 0) ? 0xFF00u : 0xFFFFu;
    bool bp = !(tid == 0 && l < 63 && t >= 2);
    int round = 0;
    while (pend || !bp) {
      if (pend) {
        if ((round & 3) == 3) {
          // ---- tier-B: agent scope (IC), guaranteed fresh ----
#pragma unroll
          for (int i = 0; i < 4; ++i) {
            const unsigned long long* sp =
                Hw + ((i < 2 ? slotCur : slotPrev) ? SLOT_STRIDE : 0) + wbase[i];
            unsigned* dp = (unsigned*)&aLds[(size_t)(kbA[i] * 64 + lnA[i]) * 8];
            const unsigned exp_ = (i < 2) ? expIn : expOwn;
#pragma unroll
            for (int j = 0; j < 4; ++j) {
              const int b_ = i * 4 + j;
              if ((pend >> b_) & 1u) {
                const unsigned long long wd =
                    __hip_atomic_load(sp + j, __ATOMIC_RELAXED, SC_AGENT);
                if ((unsigned)(wd >> 32) == exp_) {
                  dp[j] = (unsigned)wd;
                  pend &= ~(1u << b_);
                }
              }
            }
          }
        } else {
          // ---- tier-A: sc0 loads (L1-bypass, L2-served), batched ----
          u32x4 fv[8];
#pragma unroll
          for (int i = 0; i < 4; ++i) {
            if (!((pend >> (4 * i)) & 0xFu)) continue;  // group done (covers l==0 i<2)
            const unsigned long long* sp =
                Hw + ((i < 2 ? slotCur : slotPrev) ? SLOT_STRIDE : 0) + wbase[i];
            asm volatile("global_load_dwordx4 %0, %1, off sc0"
                         : "=v"(fv[2 * i]) : "v"(sp));
            asm volatile("global_load_dwordx4 %0, %1, off sc0"
                         : "=v"(fv[2 * i + 1]) : "v"(sp + 2));
          }
          asm volatile("s_waitcnt vmcnt(0)" ::: "memory");
          __builtin_amdgcn_sched_barrier(0);
#pragma unroll
          for (int i = 0; i < 4; ++i) {
            unsigned* dp = (unsigned*)&aLds[(size_t)(kbA[i] * 64 + lnA[i]) * 8];
            const unsigned exp_ = (i < 2) ? expIn : expOwn;
#pragma unroll
            for (int j = 0; j < 4; ++j) {
              const int b_ = i * 4 + j;
              if ((pend >> b_) & 1u) {
                const u32x4 va = fv[2 * i + (j >> 1)];
                const unsigned lo = va[(j & 1) * 2 + 0];
                const unsigned tg = va[(j & 1) * 2 + 1];
                if (tg == exp_) {
                  dp[j] = lo;
                  pend &= ~(1u << b_);
                }
              }
            }
          }
        }
      }
      if (!bp) {
        const int need = t - 2;
        int p0 = __hip_atomic_load(bpp0, __ATOMIC_RELAXED, SC_AGENT);
        int p1 = __hip_atomic_load(bpp1, __ATOMIC_RELAXED, SC_AGENT);
        int p2 = __hip_atomic_load(bpp2, __ATOMIC_RELAXED, SC_AGENT);
        int p3 = __hip_atomic_load(bpp3, __ATOMIC_RELAXED, SC_AGENT);
        bp = (p0 >= need) && (p1 >= need) && (p2 >= need) && (p3 >= need);
      }
      if (pend || !bp) {
        ++round;
        if (round > 2000000) break;  // hang guard: fail visibly, not dead
        if ((round & 3) == 0) __builtin_amdgcn_s_sleep(1);
      }
    }
    __syncthreads();
    if (tid == 0) __hip_atomic_store(&prog[wg], t, __ATOMIC_RELAXED, SC_AGENT);

    // ---- GEMM (unchanged) ----
    f32x4 acc[4] = {{0.f, 0.f, 0.f, 0.f}, {0.f, 0.f, 0.f, 0.f},
                    {0.f, 0.f, 0.f, 0.f}, {0.f, 0.f, 0.f, 0.f}};
#pragma unroll
    for (int kb = 0; kb < 16; ++kb) {
      half8 a = *(const half8*)&aLds[(kb * 64 + lane) * 8];
#pragma unroll
      for (int q = 0; q < 4; ++q)
        acc[q] = __builtin_amdgcn_mfma_f32_16x16x32_f16(a, wreg[q * 16 + kb], acc[q], 0, 0, 0);
    }

    // ---- z -> LDS transpose (unchanged) ----
#pragma unroll
    for (int q = 0; q < 4; ++q) {
      const int nl = (wv * 4 + q) * 16 + (lane & 15);
      const int m0 = (lane >> 4) * 4;
#pragma unroll
      for (int rg = 0; rg < 4; ++rg) zLds[(m0 + rg) * 260 + nl] = acc[q][rg];
    }
    __syncthreads();

    // ---- LSTM epilogue + register lane-pair pack + publish (no hLds) ----
    unsigned short mybits[4];
#pragma unroll
    for (int bb = 0; bb < 4; ++bb) {
      const int b = b4 * 4 + bb;
      f32x4 zg = *(const f32x4*)&zLds[b * 260 + hu * 4];  // (i,j,f,o)
      const float iv = zg[0] + bi_, jv = zg[1] + bj_;
      const float fv_ = zg[2] + bf_, ov = zg[3] + bo_;
      const float nc = sigm(fv_ + 1.0f) * creg[bb] + sigm(iv) * tanh_(jv);
      const float nh = sigm(ov) * tanh_(nc);
      creg[bb] = nc;
      union { _Float16 f; unsigned short s; } cv;
      cv.f = (_Float16)nh;
      mybits[bb] = cv.s;
      if (l == 63) out[((size_t)b * 64 + t) * 256 + gu] = nh;
    }
    {
      const unsigned p01 = mybits[0] | ((unsigned)mybits[1] << 16);
      const unsigned p23 = mybits[2] | ((unsigned)mybits[3] << 16);
      const unsigned q01 = __shfl_xor(p01, 1, 64);  // partner unit hu^1
      const unsigned q23 = __shfl_xor(p23, 1, 64);
      if (!(hu & 1)) {
        // even lane owns word (units hu, hu+1) for its 4 batches
        unsigned long long* dst = Hw + (slotCur ? SLOT_STRIDE : 0) +
                                  Widx(l, b4 * 4, r * 32 + (hu >> 1));
        const unsigned long long tg = (unsigned long long)expIn << 32;
        __hip_atomic_store(dst + 0 * 128,
            (unsigned long long)((p01 & 0xFFFFu) | (q01 << 16)) | tg,
            __ATOMIC_RELAXED, SC_AGENT);
        __hip_atomic_store(dst + 1 * 128,
            (unsigned long long)((p01 >> 16) | (q01 & 0xFFFF0000u)) | tg,
            __ATOMIC_RELAXED, SC_AGENT);
        __hip_atomic_store(dst + 2 * 128,
            (unsigned long long)((p23 & 0xFFFFu) | (q23 << 16)) | tg,
            __ATOMIC_RELAXED, SC_AGENT);
        __hip_atomic_store(dst + 3 * 128,
            (unsigned long long)((p23 >> 16) | (q23 & 0xFFFF0000u)) | tg,
            __ATOMIC_RELAXED, SC_AGENT);
      }
    }
    // no trailing barrier: next iter's staging barrier orders aLds/zLds reuse
  }
}

extern "C" void kernel_launch(void* const* d_in, const int* in_sizes, int n_in,
                              void* d_out, int out_size, void* d_ws,
                              size_t ws_size, hipStream_t stream) {
  const float* x          = (const float*)d_in[0];
  const float* init_state = (const float*)d_in[1];
  const float* W          = (const float*)d_in[2];
  const float* bias       = (const float*)d_in[3];
  float* out = (float*)d_out;
  char* ws   = (char*)d_ws;

  init_ws<<<256, 256, 0, stream>>>(init_state, ws);
  lstm_mfma<<<256, 256, 0, stream>>>(x, init_state, W, bias, out, ws);
}

// Round 4
// 767.538 us; speedup vs baseline: 1.1995x; 1.1995x over previous
//
#include <hip/hip_runtime.h>

typedef _Float16 half8 __attribute__((ext_vector_type(8)));
typedef float f32x4 __attribute__((ext_vector_type(4)));
typedef unsigned int u32x4 __attribute__((ext_vector_type(4)));

#define SC_AGENT __HIP_MEMORY_SCOPE_AGENT

// Problem: B=16, T=64, L=64, H=256. K=2H=512, N=4H=1024.
//
// Tag-in-word protocol: h published as 8B words [h0 f16 | h1 f16 | tag=t | 0]
// via agent-scope relaxed atomic store. Consumers poll their own words with
// BATCHED inline-asm agent loads (sc0 sc1, L1+L2-bypass -> IC) -- all pending
// words issued, ONE vmcnt(0), then tag-check from registers. This replaces the
// serialized per-word load+wait pattern that cost ~16 x IC-latency per step
// (the component shared by all four previous protocol variants).
//
// prog[] is indexed l*4+r (contiguous per layer) so the backpressure check is
// a single dwordx4 load. prog[l*4+r] = latest t whose staging completed.
// Producer may overwrite slot t&1 (holding t-2) once all 4 consumer WGs of
// layer l+1 have prog >= t-2.
//
// ws layout: prog[256] int at 0; Hw at 64KB: 2 slots * 64l * 16b * 128w * 8B = 2MB.
constexpr size_t OFF_PROG = 0;
constexpr size_t OFF_H    = 65536;
constexpr size_t SLOT_STRIDE = (size_t)64 * 16 * 128;  // words per slot

__device__ __forceinline__ size_t Widx(int l, int b, int wi) {
  return ((size_t)l * 16 + b) * 128 + wi;
}
__device__ __forceinline__ float sigm(float v) { return 1.0f / (1.0f + __expf(-v)); }
__device__ __forceinline__ float tanh_(float v) { return 1.0f - 2.0f / (__expf(2.0f * v) + 1.0f); }

// Batched agent-scope poll load: async; MUST be followed by vmcnt(0) +
// sched_barrier(0) before reading dst (asm outputs are load destinations).
#define POLL_LD(dst, base, OFS)                                              \
  asm volatile("global_load_dwordx2 %0, %1, off offset:" #OFS " sc0 sc1"     \
               : "=v"(dst) : "v"(base))

// ---------------- init: prog=-1, slot0 tags invalid, slot1 = h(l,-1) tag 0xFFFF ----
__global__ void init_ws(const float* __restrict__ init_state, char* ws) {
  int* prog = (int*)(ws + OFF_PROG);
  unsigned long long* Hw = (unsigned long long*)(ws + OFF_H);
  const int tid = blockIdx.x * 256 + threadIdx.x;  // 65536 threads
  if (tid < 256) prog[tid] = -1;
  for (int e = tid; e < 64 * 16 * 128; e += 65536) {
    const int wi = e & 127, b = (e >> 7) & 15, l = e >> 11;
    Hw[Widx(l, b, wi)] = 0xFFFE00000000ULL;  // slot0: tag 0xFFFE (never matches)
    union { _Float16 f; unsigned short s; } h0, h1;
    h0.f = (_Float16)init_state[((l * 2 + 1) * 16 + b) * 256 + 2 * wi];
    h1.f = (_Float16)init_state[((l * 2 + 1) * 16 + b) * 256 + 2 * wi + 1];
    Hw[SLOT_STRIDE + Widx(l, b, wi)] =
        (unsigned long long)h0.s | ((unsigned long long)h1.s << 16) | (0xFFFFULL << 32);
  }
}

// ---------------- main: 256 WGs = (layer l = wg>>2, slice r = wg&3) ----------------
__global__ __launch_bounds__(256, 1) void lstm_mfma(
    const float* __restrict__ x, const float* __restrict__ init_state,
    const float* __restrict__ W, const float* __restrict__ bias,
    float* __restrict__ out, char* ws) {
  int* prog = (int*)(ws + OFF_PROG);
  unsigned long long* Hw = (unsigned long long*)(ws + OFF_H);

  const int tid = threadIdx.x;
  const int wg = blockIdx.x;
  const int l = wg >> 2, r = wg & 3;
  const int wv = tid >> 6, lane = tid & 63;

  __shared__ alignas(16) _Float16 aLds[16 * 64 * 8];  // A-frags: [kb][lane][8], 16 KB
  __shared__ alignas(16) float zLds[16 * 260];        // z transpose, 16.6 KB
  __shared__ unsigned short hLds[16 * 64];            // nh f16 bits, 2 KB

  // ---- W slice -> registers (unchanged) ----
  half8 wreg[64];
#pragma unroll
  for (int q = 0; q < 4; ++q) {
    const int nl = (wv * 4 + q) * 16 + (lane & 15);
    const int col = (nl & 3) * 256 + r * 64 + (nl >> 2);
#pragma unroll
    for (int kb = 0; kb < 16; ++kb) {
      const int k0 = kb * 32 + (lane >> 4) * 8;
      const float* src = W + (size_t)k0 * 1024 + col;
      half8 hv;
#pragma unroll
      for (int jj = 0; jj < 8; ++jj) hv[jj] = (_Float16)src[(size_t)jj * 1024];
      wreg[q * 16 + kb] = hv;
    }
  }

  // ---- per-thread epilogue identity ----
  const int hu = tid & 63, b4 = tid >> 6;
  const int gu = r * 64 + hu;
  float creg[4];
#pragma unroll
  for (int bb = 0; bb < 4; ++bb)
    creg[bb] = init_state[((l * 2 + 0) * 16 + (b4 * 4 + bb)) * 256 + gu];
  const float bi_ = bias[0 * 256 + gu], bj_ = bias[1 * 256 + gu];
  const float bf_ = bias[2 * 256 + gu], bo_ = bias[3 * 256 + gu];

  // ---- staging entry invariants ----
  int kbA[4], lnA[4];
  size_t wbase[4];
#pragma unroll
  for (int i = 0; i < 4; ++i) {
    const int e = i * 256 + tid, kb = e >> 6, ln = e & 63;
    const int m = ln & 15, k0 = kb * 32 + (ln >> 4) * 8;
    kbA[i] = kb; lnA[i] = ln;
    wbase[i] = (i < 2) ? (l > 0 ? Widx(l - 1, m, k0 >> 1) : 0)
                       : Widx(l, m, (k0 - 256) >> 1);
  }

  int* const progIn = (l > 0) ? &prog[(l - 1) * 4 + r] : prog;
  int* const bpBase = (l < 63) ? &prog[(l + 1) * 4] : prog;

  for (int t = 0; t < 64; ++t) {
    const int slotCur = t & 1, slotPrev = (t + 1) & 1;
    const unsigned expIn = (unsigned)(unsigned short)t;        // h(l-1,t)
    const unsigned expOwn = (unsigned)(unsigned short)(t - 1); // h(l,t-1); t=0 -> 0xFFFF

    if (l == 0) {
#pragma unroll
      for (int i = 0; i < 2; ++i) {
        const int kb = kbA[i], ln = lnA[i];
        const int m = ln & 15, k0 = kb * 32 + (ln >> 4) * 8;
        const float* xs = x + ((size_t)m * 64 + t) * 256 + k0;
        half8 hv;
#pragma unroll
        for (int jj = 0; jj < 8; ++jj) hv[jj] = (_Float16)xs[jj];
        *(half8*)&aLds[(size_t)(kb * 64 + ln) * 8] = hv;
      }
    }

    // ---- coarse gate: producer layer >=1 full step behind -> sleep, don't hammer.
    // Heuristic only (tags carry correctness). All lanes read the same word.
    if (l > 0) {
      int pl = __hip_atomic_load(progIn, __ATOMIC_RELAXED, SC_AGENT);
      int g = 0;
      while (pl < t - 1) {
        __builtin_amdgcn_s_sleep(8);
        pl = __hip_atomic_load(progIn, __ATOMIC_RELAXED, SC_AGENT);
        if (++g > 400000) break;  // hang guard
      }
    }

    // ---- backpressure pre-check: tid0, ONE batched x4 load per round ----
    if (tid == 0 && l < 63 && t >= 2) {
      const int need = t - 2;
      int g = 0;
      while (true) {
        u32x4 pv;
        asm volatile("global_load_dwordx4 %0, %1, off sc0 sc1" : "=v"(pv) : "v"(bpBase));
        asm volatile("s_waitcnt vmcnt(0)" ::: "memory");
        __builtin_amdgcn_sched_barrier(0);
        if ((int)pv[0] >= need && (int)pv[1] >= need &&
            (int)pv[2] >= need && (int)pv[3] >= need) break;
        __builtin_amdgcn_s_sleep(2);
        if (++g > 400000) break;  // hang guard
      }
    }

    // ---- poll+stage: batched issue -> one vmcnt(0) -> tag-check ----
    unsigned pend = (l == 0) ? 0xFF00u : 0xFFFFu;
    int round = 0;
    while (pend) {
      unsigned long long wv_[16];
      const unsigned long long* sp0 = Hw + (slotCur ? SLOT_STRIDE : 0) + wbase[0];
      const unsigned long long* sp1 = Hw + (slotCur ? SLOT_STRIDE : 0) + wbase[1];
      const unsigned long long* sp2 = Hw + (slotPrev ? SLOT_STRIDE : 0) + wbase[2];
      const unsigned long long* sp3 = Hw + (slotPrev ? SLOT_STRIDE : 0) + wbase[3];
      if (pend & 0x0001u) POLL_LD(wv_[0],  sp0, 0);
      if (pend & 0x0002u) POLL_LD(wv_[1],  sp0, 8);
      if (pend & 0x0004u) POLL_LD(wv_[2],  sp0, 16);
      if (pend & 0x0008u) POLL_LD(wv_[3],  sp0, 24);
      if (pend & 0x0010u) POLL_LD(wv_[4],  sp1, 0);
      if (pend & 0x0020u) POLL_LD(wv_[5],  sp1, 8);
      if (pend & 0x0040u) POLL_LD(wv_[6],  sp1, 16);
      if (pend & 0x0080u) POLL_LD(wv_[7],  sp1, 24);
      if (pend & 0x0100u) POLL_LD(wv_[8],  sp2, 0);
      if (pend & 0x0200u) POLL_LD(wv_[9],  sp2, 8);
      if (pend & 0x0400u) POLL_LD(wv_[10], sp2, 16);
      if (pend & 0x0800u) POLL_LD(wv_[11], sp2, 24);
      if (pend & 0x1000u) POLL_LD(wv_[12], sp3, 0);
      if (pend & 0x2000u) POLL_LD(wv_[13], sp3, 8);
      if (pend & 0x4000u) POLL_LD(wv_[14], sp3, 16);
      if (pend & 0x8000u) POLL_LD(wv_[15], sp3, 24);
      asm volatile("s_waitcnt vmcnt(0)" ::: "memory");
      __builtin_amdgcn_sched_barrier(0);
#pragma unroll
      for (int i = 0; i < 4; ++i) {
        unsigned* dp = (unsigned*)&aLds[(size_t)(kbA[i] * 64 + lnA[i]) * 8];
        const unsigned exp_ = (i < 2) ? expIn : expOwn;
#pragma unroll
        for (int j = 0; j < 4; ++j) {
          const int b_ = i * 4 + j;
          if ((pend >> b_) & 1u) {
            const unsigned long long wd = wv_[b_];
            if ((unsigned)(wd >> 32) == exp_) {
              dp[j] = (unsigned)wd;  // low 32b = two f16 h values
              pend &= ~(1u << b_);
            }
          }
        }
      }
      if (pend) {
        if (++round > 500000) break;  // hang guard: fail visibly, not dead
        if ((round & 15) == 0) __builtin_amdgcn_s_sleep(1);
      }
    }
    __syncthreads();
    if (tid == 0) __hip_atomic_store(&prog[l * 4 + r], t, __ATOMIC_RELAXED, SC_AGENT);

    // ---- GEMM (unchanged) ----
    f32x4 acc[4] = {{0.f, 0.f, 0.f, 0.f}, {0.f, 0.f, 0.f, 0.f},
                    {0.f, 0.f, 0.f, 0.f}, {0.f, 0.f, 0.f, 0.f}};
#pragma unroll
    for (int kb = 0; kb < 16; ++kb) {
      half8 a = *(const half8*)&aLds[(kb * 64 + lane) * 8];
#pragma unroll
      for (int q = 0; q < 4; ++q)
        acc[q] = __builtin_amdgcn_mfma_f32_16x16x32_f16(a, wreg[q * 16 + kb], acc[q], 0, 0, 0);
    }

    // ---- z -> LDS transpose (unchanged) ----
#pragma unroll
    for (int q = 0; q < 4; ++q) {
      const int nl = (wv * 4 + q) * 16 + (lane & 15);
      const int m0 = (lane >> 4) * 4;
#pragma unroll
      for (int rg = 0; rg < 4; ++rg) zLds[(m0 + rg) * 260 + nl] = acc[q][rg];
    }
    __syncthreads();

    // ---- LSTM epilogue (unchanged) ----
#pragma unroll
    for (int bb = 0; bb < 4; ++bb) {
      const int b = b4 * 4 + bb;
      f32x4 zg = *(const f32x4*)&zLds[b * 260 + hu * 4];  // (i,j,f,o)
      const float iv = zg[0] + bi_, jv = zg[1] + bj_;
      const float fv = zg[2] + bf_, ov = zg[3] + bo_;
      const float nc = sigm(fv + 1.0f) * creg[bb] + sigm(iv) * tanh_(jv);
      const float nh = sigm(ov) * tanh_(nc);
      creg[bb] = nc;
      union { _Float16 f; unsigned short s; } cv;
      cv.f = (_Float16)nh;
      hLds[b * 64 + hu] = cv.s;
      if (l == 63) out[((size_t)b * 64 + t) * 256 + gu] = nh;
    }
    __syncthreads();

    // ---- publish: tagged words, fire-and-forget agent stores ----
    {
      const int b = tid >> 4, lw0 = (tid & 15) * 2;
#pragma unroll
      for (int q = 0; q < 2; ++q) {
        const int lw = lw0 + q, u0 = 2 * lw;
        unsigned lo = (unsigned)hLds[b * 64 + u0] | ((unsigned)hLds[b * 64 + u0 + 1] << 16);
        unsigned long long wd =
            (unsigned long long)lo | ((unsigned long long)expIn << 32);
        __hip_atomic_store(Hw + (slotCur ? SLOT_STRIDE : 0) + Widx(l, b, r * 32 + lw),
                           wd, __ATOMIC_RELAXED, SC_AGENT);
      }
    }
    // no trailing barrier: next iter's staging barrier orders aLds/hLds reuse
  }
}

extern "C" void kernel_launch(void* const* d_in, const int* in_sizes, int n_in,
                              void* d_out, int out_size, void* d_ws,
                              size_t ws_size, hipStream_t stream) {
  const float* x          = (const float*)d_in[0];
  const float* init_state = (const float*)d_in[1];
  const float* W          = (const float*)d_in[2];
  const float* bias       = (const float*)d_in[3];
  float* out = (float*)d_out;
  char* ws   = (char*)d_ws;

  init_ws<<<256, 256, 0, stream>>>(init_state, ws);
  lstm_mfma<<<256, 256, 0, stream>>>(x, init_state, W, bias, out, ws);
}